// Round 20
// baseline (154.578 us; speedup 1.0000x reference)
//
#include <hip/hip_runtime.h>
#include <stdint.h>

constexpr int B = 4;
constexpr int N = 262144;
constexpr int C = 10;
constexpr int KPRE = 4096;
constexpr int KPOST = 500;
constexpr float ROI_THR = 0.1f;
constexpr float NMS_THR = 0.01f;
constexpr int CAP = 8192;        // compaction capacity (>= KPRE + boundary-bin ties)
constexpr int MASKW = KPRE / 64; // 64 u64 words per mask row
constexpr int RJT = 2;           // j-tiles per rank block
constexpr int NJCH = CAP / (256 * RJT); // 16 j-chunks per i-tile
constexpr int MAXP = 32;         // deferred alive-row slots in nms

__device__ __forceinline__ uint32_t f2k(float f) {
  uint32_t u = __float_as_uint(f);
  return (u & 0x80000000u) ? ~u : (u | 0x80000000u);
}
__device__ __forceinline__ float k2f(uint32_t k) {
  uint32_t u = (k & 0x80000000u) ? (k ^ 0x80000000u) : ~k;
  return __uint_as_float(u);
}
__device__ __forceinline__ float sigm(float x) { return 1.0f / (1.0f + expf(-x)); }

__device__ __forceinline__ void async_lds16(const void* g, void* l) {
  __builtin_amdgcn_global_load_lds((const __attribute__((address_space(1))) void*)g,
                                   (__attribute__((address_space(3))) void*)l, 16, 0, 0);
}

// Suffix-select on a 256-bin histogram: returns (bin, residual rank). blockDim==256.
__device__ __forceinline__ uint2 select256(const uint32_t* __restrict__ h, uint32_t R,
                                           uint32_t* s, uint32_t* o2) {
  int t = threadIdx.x;
  s[t] = h[t];
  __syncthreads();
  for (int off = 1; off < 256; off <<= 1) {
    uint32_t v = s[t] + ((t + off < 256) ? s[t + off] : 0u);
    __syncthreads();
    s[t] = v;
    __syncthreads();
  }
  uint32_t suf = s[t];
  uint32_t sufn = (t < 255) ? s[t + 1] : 0u;
  if (suf >= R && R > sufn) {
    o2[0] = (uint32_t)t;
    o2[1] = R - sufn;
  }
  __syncthreads();
  uint2 r;
  r.x = o2[0];
  r.y = o2[1];
  __syncthreads(); // protect scratch reuse
  return r;
}

// ---------------- K0: zero the aliased scratch ----------------
__global__ void zeroK(uint32_t* __restrict__ p, int n) {
  int i = blockIdx.x * 256 + threadIdx.x;
  if (i < n) p[i] = 0u;
}

// ---------------- K1: keys + pass-0 hist + speculative byte-1 hist (byte0==0xBF) ----------------
// 0xBF is the byte-0 bin of scores in [0.5,1); rank-4096 lands there on this data, so hist1
// equals the byte-1 histogram a dedicated pass would compute (R19-verified). Fallback in
// compactK uses a byte-0-only threshold (exact whenever byte-0 suffix <= CAP).
__global__ void scoreK(const float* __restrict__ cls, uint32_t* __restrict__ keys,
                       uint32_t* __restrict__ hist0, uint32_t* __restrict__ hist1) {
  __shared__ float ls[2560]; // 256 items x 10 classes
  __shared__ uint32_t h[256];
  __shared__ uint32_t h1[256];
  int b = blockIdx.y;
  int t = threadIdx.x;
  h[t] = 0;
  h1[t] = 0;
  size_t base = ((size_t)b * N + (size_t)blockIdx.x * 256) * C;
  const float2* g2 = (const float2*)(cls + base);
  float2* l2 = (float2*)ls;
#pragma unroll
  for (int r = 0; r < 5; ++r) l2[r * 256 + t] = g2[r * 256 + t]; // coalesced 512B/wave
  __syncthreads();
  const float* mine = ls + t * 10;
  float m = mine[0];
#pragma unroll
  for (int c = 1; c < C; ++c) m = fmaxf(m, mine[c]); // max logit
  float p = sigm(m);                                  // == max prob (monotone)
  float sc = (p > ROI_THR) ? p : -1.0f;
  uint32_t k = f2k(sc);
  keys[(size_t)b * N + blockIdx.x * 256 + t] = k;
  atomicAdd(&h[k >> 24], 1u);
  if ((k >> 24) == 0xBFu) atomicAdd(&h1[(k >> 16) & 255u], 1u);
  __syncthreads();
  if (h[t]) atomicAdd(&hist0[b * 256 + t], h[t]);
  if (h1[t]) atomicAdd(&hist1[b * 256 + t], h1[t]);
}

// ---------------- K2: threshold + block-aggregated stream compaction ----------------
__global__ void compactK(const uint32_t* __restrict__ keys, const uint32_t* __restrict__ hist0,
                         const uint32_t* __restrict__ hist1,
                         unsigned long long* __restrict__ list, uint32_t* __restrict__ cnt) {
  __shared__ uint32_t s[256];
  __shared__ uint32_t o2[2];
  __shared__ uint32_t scan[256];
  __shared__ uint32_t baseSh;
  int b = blockIdx.y;
  int t = threadIdx.x;
  uint2 s0 = select256(hist0 + b * 256, (uint32_t)KPRE, s, o2);
  uint32_t T;
  if (s0.x == 0xBFu) { // speculative hist1 valid (verified path)
    uint2 s1 = select256(hist1 + b * 256, s0.y, s, o2);
    T = ((s0.x << 8) | s1.x) << 16;
  } else {
    T = s0.x << 24; // byte-0-only threshold: exact while byte-0 suffix <= CAP
  }
  const uint4* kb4 = (const uint4*)(keys + (size_t)b * N);
  uint4 kv[4];
#pragma unroll
  for (int r = 0; r < 4; ++r) kv[r] = kb4[blockIdx.x * 1024 + r * 256 + t];
  uint32_t c = 0;
#pragma unroll
  for (int r = 0; r < 4; ++r)
#pragma unroll
    for (int j = 0; j < 4; ++j) c += ((&kv[r].x)[j] >= T) ? 1u : 0u;
  scan[t] = c;
  __syncthreads();
  for (int off = 1; off < 256; off <<= 1) {
    uint32_t v = scan[t] + ((t >= off) ? scan[t - off] : 0u);
    __syncthreads();
    scan[t] = v;
    __syncthreads();
  }
  uint32_t excl = scan[t] - c;
  if (t == 255) baseSh = atomicAdd(&cnt[b], scan[255]);
  __syncthreads();
  uint32_t pos = baseSh + excl;
#pragma unroll
  for (int r = 0; r < 4; ++r)
#pragma unroll
    for (int j = 0; j < 4; ++j) {
      uint32_t k = (&kv[r].x)[j];
      if (k >= T) {
        uint32_t n = (blockIdx.x * 1024 + r * 256 + t) * 4 + j;
        if (pos < CAP)
          list[(size_t)b * CAP + pos] = ((unsigned long long)k << 32) | (uint32_t)(~n);
        pos++;
      }
    }
}

// ---------------- K3: fused rank-by-counting + scatter ----------------
// Grid (32 i-tiles, 16 j-chunks, B). Each block adds its partial rank counts, then
// increments done[b][itile]; the 16th arriver re-reads ranks (coherent atomic loads —
// __syncthreads drained this block's atomics before the done increment) and scatters.
__global__ void rankscatK(const unsigned long long* __restrict__ list,
                          const uint32_t* __restrict__ cnt, uint32_t* __restrict__ rank,
                          uint32_t* __restrict__ done, const float* __restrict__ boxes,
                          float* __restrict__ sel_score, uint32_t* __restrict__ sel_idx,
                          float* __restrict__ sel_box) {
  __shared__ unsigned long long lp[256];
  __shared__ uint32_t lastSh;
  int b = blockIdx.z;
  int itile = blockIdx.x;
  int t = threadIdx.x;
  int cc = (int)min(cnt[b], (uint32_t)CAP);
  int i = itile * 256 + t;
  if (itile * 256 < cc) {
    int j0 = blockIdx.y * (256 * RJT);
    if (j0 < cc) {
      unsigned long long pi = (i < cc) ? list[(size_t)b * CAP + i] : ~0ull;
      uint32_t c = 0;
#pragma unroll
      for (int tb = 0; tb < RJT; ++tb) {
        int j = j0 + tb * 256 + t;
        __syncthreads();
        lp[t] = (j < cc) ? list[(size_t)b * CAP + j] : 0ull;
        __syncthreads();
#pragma unroll 8
        for (int jj = 0; jj < 256; ++jj) c += (lp[jj] > pi) ? 1u : 0u;
      }
      if (i < cc && c) atomicAdd(&rank[(size_t)b * CAP + i], c);
    }
  }
  __syncthreads(); // drains this block's outstanding atomics (waitcnt at barrier)
  if (t == 0) lastSh = atomicAdd(&done[b * 32 + itile], 1u);
  __syncthreads();
  if (lastSh == NJCH - 1 && i < cc) { // last block for this i-tile: scatter
    unsigned long long pk = list[(size_t)b * CAP + i];
    uint32_t r = atomicAdd(&rank[(size_t)b * CAP + i], 0u); // coherent read
    if (r < (uint32_t)KPRE) {
      uint32_t key = (uint32_t)(pk >> 32);
      uint32_t idx = ~(uint32_t)pk;
      sel_score[b * KPRE + r] = k2f(key);
      sel_idx[b * KPRE + r] = idx;
      const float* src = boxes + ((size_t)b * N + idx) * 7;
      float* dst = sel_box + ((size_t)b * KPRE + r) * 8;
#pragma unroll
      for (int c7 = 0; c7 < 7; ++c7) dst[c7] = src[c7];
      dst[7] = 0.f;
    }
  }
}

// ---------------- K4: IoU bitmask — 64x64 tiles, 1 wave/block, transposed store ----------------
template <bool CHK>
__device__ __forceinline__ void mask_row64(int tt, const float4* __restrict__ jv,
                                           const float* __restrict__ ja, float x1i, float x2i,
                                           float y1i, float y2i, float ai, uint32_t& lo0,
                                           uint32_t& hi0, uint32_t& band) {
#pragma unroll 16
  for (int jj = 0; jj < 64; ++jj) {
    float4 v = jv[jj];
    float aj = ja[jj];
    float xx1 = fmaxf(x1i, v.x), xx2 = fminf(x2i, v.y);
    float yy1 = fmaxf(y1i, v.z), yy2 = fminf(y2i, v.w);
    float ix = fmaxf(__fsub_rn(xx2, xx1), 0.0f), iy = fmaxf(__fsub_rn(yy2, yy1), 0.0f);
    float inter = __fmul_rn(ix, iy);
    float den = fmaxf(__fsub_rn(__fadd_rn(ai, aj), inter), 1e-6f);
    float q0 = __fmul_rn(NMS_THR, den);
    float d = __fsub_rn(inter, q0);
    band |= (fabsf(d) <= __fmul_rn(q0, 1e-5f)) ? 1u : 0u;
    bool sup = d > 0.0f;
    if (CHK) sup = sup && (jj > tt);
    uint32_t bit = sup ? 1u : 0u;
    if (jj < 32) lo0 |= bit << jj; else hi0 |= bit << (jj - 32);
  }
}

__global__ __launch_bounds__(64) void maskK(const float* __restrict__ sel_box,
                                            unsigned long long* __restrict__ maskT,
                                            unsigned long long* __restrict__ Tmat) {
  int b = blockIdx.z;
  int bi = blockIdx.x; // 64-row tile
  int w = blockIdx.y;  // 64-col word
  if (w < bi) return;  // below diagonal: never read (nms loads predicated t>=g)
  int t = threadIdx.x; // 0..63
  int i = bi * 64 + t;
  int j0 = w * 64;
  __shared__ float4 jv[64]; // {x1, x2, y1, y2}
  __shared__ float ja[64];
  {
    const float4* bj = (const float4*)(sel_box + ((size_t)b * KPRE + j0 + t) * 8);
    float4 lo = bj[0], hi = bj[1];
    float xj = lo.x, yj = lo.y, dxj = lo.w, dyj = hi.x;
    float hxj = __fmul_rn(dxj, 0.5f), hyj = __fmul_rn(dyj, 0.5f);
    float4 v;
    v.x = __fsub_rn(xj, hxj);
    v.y = __fadd_rn(xj, hxj);
    v.z = __fsub_rn(yj, hyj);
    v.w = __fadd_rn(yj, hyj);
    jv[t] = v;
    ja[t] = __fmul_rn(dxj, dyj);
  }
  __syncthreads();
  const float4* myb = (const float4*)(sel_box + ((size_t)b * KPRE + i) * 8);
  float4 lo = myb[0], hi = myb[1];
  float x = lo.x, y = lo.y, dx = lo.w, dy = hi.x;
  float hx = __fmul_rn(dx, 0.5f), hy = __fmul_rn(dy, 0.5f);
  float x1i = __fsub_rn(x, hx), x2i = __fadd_rn(x, hx);
  float y1i = __fsub_rn(y, hy), y2i = __fadd_rn(y, hy);
  float ai = __fmul_rn(dx, dy);
  uint32_t lo0 = 0, hi0 = 0, band = 0;
  if (w == bi)
    mask_row64<true>(t, jv, ja, x1i, x2i, y1i, y2i, ai, lo0, hi0, band);
  else
    mask_row64<false>(t, jv, ja, x1i, x2i, y1i, y2i, ai, lo0, hi0, band);
  if (__builtin_expect(__any(band != 0), 0)) { // rare: exact IEEE replay of whole tile
    lo0 = hi0 = 0;
    for (int jj = 0; jj < 64; ++jj) {
      float4 v = jv[jj];
      float aj = ja[jj];
      float xx1 = fmaxf(x1i, v.x), xx2 = fminf(x2i, v.y);
      float yy1 = fmaxf(y1i, v.z), yy2 = fminf(y2i, v.w);
      float ix = fmaxf(__fsub_rn(xx2, xx1), 0.0f), iy = fmaxf(__fsub_rn(yy2, yy1), 0.0f);
      float inter = __fmul_rn(ix, iy);
      float den = fmaxf(__fsub_rn(__fadd_rn(ai, aj), inter), 1e-6f);
      bool sup = (inter / den) > NMS_THR && (j0 + jj > i);
      uint32_t bit = sup ? 1u : 0u;
      if (jj < 32) lo0 |= bit << jj; else hi0 |= bit << (jj - 32);
    }
  }
  unsigned long long wacc = ((unsigned long long)hi0 << 32) | lo0;
  maskT[((size_t)b * MASKW + w) * KPRE + i] = wacc; // coalesced: lanes -> consecutive rows
  if (w == bi) { // fused diag transpose: this wave IS group w's diagonal block
    unsigned long long m = wacc;
    unsigned long long T = 0ull;
#pragma unroll
    for (int j = 0; j < 64; ++j) {
      unsigned long long bj = __ballot(((m >> j) & 1ull) != 0ull);
      if (t == j) T = bj;
    }
    unsigned long long* trow = Tmat + ((size_t)b * 64 + w) * 128;
    trow[t] = T;
    trow[64 + t] = m;
  }
}

// ---------------- K5: greedy NMS + fused output emission (1 wave / batch) ----------------
__global__ void nmsoutK(const unsigned long long* __restrict__ maskT,
                        const unsigned long long* __restrict__ Tmat,
                        const float* __restrict__ sel_score,
                        const uint32_t* __restrict__ sel_idx,
                        const float* __restrict__ sel_box, const float* __restrict__ cls,
                        float* __restrict__ out) {
  __shared__ unsigned long long td[64][128]; // 64 KiB resident [T | diag]
  __shared__ uint32_t keptbuf[KPOST];
  int b = blockIdx.x;
  int t = threadIdx.x; // lane 0..63; owns remv word t

  const char* tsrc = (const char*)(Tmat + (size_t)b * 64 * 128);
  for (int g = 0; g < 64; ++g)
    async_lds16(tsrc + (size_t)g * 1024 + (size_t)t * 16, &td[g][0]);

  unsigned long long cand = 0ull; // overlaps with TD load latency
  for (int k = 0; k < 64; ++k) {
    float s = sel_score[b * KPRE + k * 64 + t];
    unsigned long long bal = __ballot(s > ROI_THR);
    if (t == k) cand = bal;
  }
  asm volatile("s_waitcnt vmcnt(0)" ::: "memory"); // TD resident (single wave, no barrier)

  const unsigned long long* mbt = maskT + (size_t)b * KPRE * MASKW + (size_t)t * KPRE;
  unsigned long long remv = 0ull;
  unsigned long long r[MAXP];
#pragma unroll
  for (int a = 0; a < MAXP; ++a) r[a] = 0ull;
  int kc = 0;

  for (int g = 0; g < 64; ++g) {
#pragma unroll
    for (int a = 0; a < MAXP; ++a) remv |= r[a]; // deferred ORs (waits loads at first use)

    unsigned long long cw = cand & ~remv;
    unsigned long long aw =
        ((unsigned long long)(uint32_t)__builtin_amdgcn_readlane((uint32_t)(cw >> 32), g) << 32) |
        (uint32_t)__builtin_amdgcn_readlane((uint32_t)cw, g);
    if (aw) {
      unsigned long long T = td[g][t];      // who kills me (bits < t)
      unsigned long long m = td[g][64 + t]; // who I kill (bits > t)
      unsigned long long K = __ballot((m & aw) != 0ull);
      unsigned long long alive = aw;
      unsigned long long rem = aw & K;
      if (rem) {
        bool deadf = ((aw >> t) & 1ull) == 0ull;
        while (rem) {
          int s = __ffsll((long long)rem) - 1;
          rem &= rem - 1ull;
          if ((alive >> s) & 1ull) { // s is final-alive here (ascending order)
            deadf = deadf || (((T >> s) & 1ull) != 0ull);
            alive = __ballot(!deadf);
            rem &= alive;
          }
        }
      }
      int grp = __popcll(alive);
      if ((alive >> t) & 1ull) {
        int rk = __popcll(alive & ((1ull << t) - 1ull));
        if (kc + rk < KPOST) keptbuf[kc + rk] = (uint32_t)(g * 64 + t);
      }
      kc += grp;
      unsigned long long a2 = alive;
      bool again = true;
      while (again) {
#pragma unroll
        for (int a = 0; a < MAXP; ++a) {
          if (a2) {
            int s2 = __ffsll((long long)a2) - 1;
            a2 &= a2 - 1ull;
            r[a] = (t >= g) ? mbt[g * 64 + s2] : 0ull; // predicated: t<g words unwritten==0
          } else {
            r[a] = 0ull;
          }
        }
        if (a2) { // overflow batch: absorb now, go again
#pragma unroll
          for (int a = 0; a < MAXP; ++a) {
            remv |= r[a];
            r[a] = 0ull;
          }
          again = true;
        } else {
          again = false; // final batch deferred to next group's top
        }
      }
      if (kc >= KPOST) break;
    } else {
#pragma unroll
      for (int a = 0; a < MAXP; ++a) r[a] = 0ull; // nothing new in flight
    }
  }
  asm volatile("s_waitcnt vmcnt(0)" ::: "memory"); // drain in-flight row loads
  int kcc = min(kc, KPOST);

  // ---- fused output emission (keptbuf is wave-local LDS) ----
  float* oS = out;                             // (B, KPOST)
  float* oB = out + B * KPOST;                 // (B, KPOST, 7)
  float* oL = out + B * KPOST + B * KPOST * 7; // (B, KPOST)
  for (int s = t; s < KPOST; s += 64) {
    if (s < kcc) {
      uint32_t pos = keptbuf[s];
      oS[b * KPOST + s] = sel_score[b * KPRE + pos];
      const float* box = sel_box + ((size_t)b * KPRE + pos) * 8;
      float* dst = oB + ((size_t)b * KPOST + s) * 7;
#pragma unroll
      for (int c = 0; c < 7; ++c) dst[c] = box[c];
      uint32_t idx = sel_idx[b * KPRE + pos];
      const float* p = cls + ((size_t)b * N + idx) * C;
      float bestv = sigm(p[0]);
      int bestc = 0;
#pragma unroll
      for (int c = 1; c < C; ++c) {
        float v = sigm(p[c]);
        if (v > bestv) { bestv = v; bestc = c; }
      }
      oL[b * KPOST + s] = (float)bestc;
    } else {
      oS[b * KPOST + s] = 0.0f;
      float* dst = oB + ((size_t)b * KPOST + s) * 7;
#pragma unroll
      for (int c = 0; c < 7; ++c) dst[c] = 0.0f;
      oL[b * KPOST + s] = -1.0f;
    }
  }
}

__global__ void sentinelK(float* out, int n) {
  int i = blockIdx.x * blockDim.x + threadIdx.x;
  if (i < n) out[i] = 1337.0f;
}

extern "C" void kernel_launch(void* const* d_in, const int* in_sizes, int n_in,
                              void* d_out, int out_size, void* d_ws, size_t ws_size,
                              hipStream_t stream) {
  const float* cls = (const float*)d_in[0];
  const float* boxes = (const float*)d_in[1];
  float* out = (float*)d_out;

  char* ws = (char*)d_ws;
  size_t off = 0;
  auto alloc = [&](size_t bytes) -> void* {
    void* p = ws + off;
    off = (off + bytes + 255) & ~(size_t)255;
    return p;
  };
  size_t mask_bytes = (size_t)B * KPRE * MASKW * 8; // 8 MB
  unsigned long long* mask = (unsigned long long*)alloc(mask_bytes); // TRANSPOSED [b][word][row]
  unsigned long long* list = (unsigned long long*)alloc((size_t)B * CAP * 8);
  uint32_t* keys = (uint32_t*)alloc((size_t)B * N * 4);
  float* sel_box = (float*)alloc((size_t)B * KPRE * 8 * 4);
  float* sel_score = (float*)alloc((size_t)B * KPRE * 4);
  uint32_t* sel_idx = (uint32_t*)alloc((size_t)B * KPRE * 4);
  unsigned long long* Tmat = (unsigned long long*)alloc((size_t)B * 64 * 128 * 8); // 256 KB

  // Aliases into the mask region — all dead before maskK writes mask. Header (<16KB):
  // hist0, hist1, cnt, done; rank at byte 16384. All zeroed by zeroK each call.
  uint32_t* hist0 = (uint32_t*)mask;
  uint32_t* hist1 = hist0 + B * 256;
  uint32_t* cnt = hist1 + B * 256;
  uint32_t* done = cnt + B;           // B*32 u32
  uint32_t* rank = (uint32_t*)((char*)mask + 16384);
  int zwords = (16384 + B * CAP * 4) / 4; // header + rank

  if (off > ws_size) {
    sentinelK<<<dim3((out_size + 255) / 256), 256, 0, stream>>>(out, out_size);
    return;
  }

  zeroK<<<dim3((zwords + 255) / 256), 256, 0, stream>>>((uint32_t*)mask, zwords);
  scoreK<<<dim3(N / 256, B), 256, 0, stream>>>(cls, keys, hist0, hist1);
  compactK<<<dim3(N / 4096, B), 256, 0, stream>>>(keys, hist0, hist1, list, cnt);
  rankscatK<<<dim3(CAP / 256, NJCH, B), 256, 0, stream>>>(list, cnt, rank, done, boxes, sel_score,
                                                          sel_idx, sel_box);
  maskK<<<dim3(64, 64, B), 64, 0, stream>>>(sel_box, mask, Tmat);
  nmsoutK<<<B, 64, 0, stream>>>(mask, Tmat, sel_score, sel_idx, sel_box, cls, out);
}

// Round 21
// 141.274 us; speedup vs baseline: 1.0942x; 1.0942x over previous
//
#include <hip/hip_runtime.h>
#include <stdint.h>

constexpr int B = 4;
constexpr int N = 262144;
constexpr int C = 10;
constexpr int KPRE = 4096;
constexpr int KPOST = 500;
constexpr float ROI_THR = 0.1f;
constexpr float NMS_THR = 0.01f;
constexpr int CAP = 8192;        // compaction capacity (>= KPRE + boundary-bin ties)
constexpr int MASKW = KPRE / 64; // 64 u64 words per mask row
constexpr int RJT = 2;           // j-tiles per rankK block
constexpr int MAXP = 32;         // deferred alive-row slots in nmsK

__device__ __forceinline__ uint32_t f2k(float f) {
  uint32_t u = __float_as_uint(f);
  return (u & 0x80000000u) ? ~u : (u | 0x80000000u);
}
__device__ __forceinline__ float k2f(uint32_t k) {
  uint32_t u = (k & 0x80000000u) ? (k ^ 0x80000000u) : ~k;
  return __uint_as_float(u);
}
__device__ __forceinline__ float sigm(float x) { return 1.0f / (1.0f + expf(-x)); }

__device__ __forceinline__ void async_lds16(const void* g, void* l) {
  __builtin_amdgcn_global_load_lds((const __attribute__((address_space(1))) void*)g,
                                   (__attribute__((address_space(3))) void*)l, 16, 0, 0);
}

// Suffix-select on a 256-bin histogram: returns (bin, residual rank). blockDim==256.
__device__ __forceinline__ uint2 select256(const uint32_t* __restrict__ h, uint32_t R,
                                           uint32_t* s, uint32_t* o2) {
  int t = threadIdx.x;
  s[t] = h[t];
  __syncthreads();
  for (int off = 1; off < 256; off <<= 1) {
    uint32_t v = s[t] + ((t + off < 256) ? s[t + off] : 0u);
    __syncthreads();
    s[t] = v;
    __syncthreads();
  }
  uint32_t suf = s[t];
  uint32_t sufn = (t < 255) ? s[t + 1] : 0u;
  if (suf >= R && R > sufn) {
    o2[0] = (uint32_t)t;
    o2[1] = R - sufn;
  }
  __syncthreads();
  uint2 r;
  r.x = o2[0];
  r.y = o2[1];
  __syncthreads(); // protect scratch reuse
  return r;
}

// ---------------- K-1: zero the aliased scratch (custom: cheap, launch-bound) ----------------
__global__ void zeroK(uint32_t* __restrict__ p, int n) {
  int i = blockIdx.x * 256 + threadIdx.x;
  if (i < n) p[i] = 0u;
}

// ---------------- K0: keys + pass-0 histogram (sigmoid commutes with max) ----------------
__global__ void scoreK(const float* __restrict__ cls, uint32_t* __restrict__ keys,
                       uint32_t* __restrict__ hist0) {
  __shared__ float ls[2560]; // 256 items x 10 classes
  __shared__ uint32_t h[256];
  int b = blockIdx.y;
  int t = threadIdx.x;
  h[t] = 0;
  size_t base = ((size_t)b * N + (size_t)blockIdx.x * 256) * C;
  const float2* g2 = (const float2*)(cls + base);
  float2* l2 = (float2*)ls;
#pragma unroll
  for (int r = 0; r < 5; ++r) l2[r * 256 + t] = g2[r * 256 + t]; // coalesced 512B/wave
  __syncthreads();
  const float* mine = ls + t * 10;
  float m = mine[0];
#pragma unroll
  for (int c = 1; c < C; ++c) m = fmaxf(m, mine[c]); // max logit
  float p = sigm(m);                                  // == max prob (monotone)
  float sc = (p > ROI_THR) ? p : -1.0f;
  uint32_t k = f2k(sc);
  keys[(size_t)b * N + blockIdx.x * 256 + t] = k;
  atomicAdd(&h[k >> 24], 1u);
  __syncthreads();
  if (h[t]) atomicAdd(&hist0[b * 256 + t], h[t]);
}

// ---------------- K1: byte-1 histogram among items matching pass-0 byte ----------------
__global__ void histP1K(const uint32_t* __restrict__ keys, const uint32_t* __restrict__ hist0,
                        uint32_t* __restrict__ hist1) {
  __shared__ uint32_t s[256];
  __shared__ uint32_t o2[2];
  __shared__ uint32_t h[256];
  int b = blockIdx.y;
  int t = threadIdx.x;
  uint2 s0 = select256(hist0 + b * 256, (uint32_t)KPRE, s, o2);
  h[t] = 0;
  __syncthreads();
  uint32_t pref = s0.x;
  const uint4* kb4 = (const uint4*)(keys + (size_t)b * N);
#pragma unroll
  for (int r = 0; r < 2; ++r) {
    uint4 kv = kb4[blockIdx.x * 512 + r * 256 + t];
#pragma unroll
    for (int j = 0; j < 4; ++j) {
      uint32_t k = (&kv.x)[j];
      if ((k >> 24) == pref) atomicAdd(&h[(k >> 16) & 255u], 1u);
    }
  }
  __syncthreads();
  if (h[t]) atomicAdd(&hist1[b * 256 + t], h[t]);
}

// ---------------- K2: 16-bit threshold; block-aggregated stream compaction ----------------
__global__ void compactK(const uint32_t* __restrict__ keys, const uint32_t* __restrict__ hist0,
                         const uint32_t* __restrict__ hist1, unsigned long long* __restrict__ list,
                         uint32_t* __restrict__ cnt) {
  __shared__ uint32_t s[256];
  __shared__ uint32_t o2[2];
  __shared__ uint32_t scan[256];
  __shared__ uint32_t baseSh;
  int b = blockIdx.y;
  int t = threadIdx.x;
  uint2 s0 = select256(hist0 + b * 256, (uint32_t)KPRE, s, o2);
  uint2 s1 = select256(hist1 + b * 256, s0.y, s, o2);
  uint32_t T = ((s0.x << 8) | s1.x) << 16;
  const uint4* kb4 = (const uint4*)(keys + (size_t)b * N);
  uint4 kv[4];
#pragma unroll
  for (int r = 0; r < 4; ++r) kv[r] = kb4[blockIdx.x * 1024 + r * 256 + t];
  uint32_t c = 0;
#pragma unroll
  for (int r = 0; r < 4; ++r)
#pragma unroll
    for (int j = 0; j < 4; ++j) c += ((&kv[r].x)[j] >= T) ? 1u : 0u;
  scan[t] = c;
  __syncthreads();
  for (int off = 1; off < 256; off <<= 1) {
    uint32_t v = scan[t] + ((t >= off) ? scan[t - off] : 0u);
    __syncthreads();
    scan[t] = v;
    __syncthreads();
  }
  uint32_t excl = scan[t] - c;
  if (t == 255) baseSh = atomicAdd(&cnt[b], scan[255]);
  __syncthreads();
  uint32_t pos = baseSh + excl;
#pragma unroll
  for (int r = 0; r < 4; ++r)
#pragma unroll
    for (int j = 0; j < 4; ++j) {
      uint32_t k = (&kv[r].x)[j];
      if (k >= T) {
        uint32_t n = (blockIdx.x * 1024 + r * 256 + t) * 4 + j;
        if (pos < CAP)
          list[(size_t)b * CAP + pos] = ((unsigned long long)k << 32) | (uint32_t)(~n);
        pos++;
      }
    }
}

// ---------------- K3: exact rank by counting, j-split for occupancy ----------------
__global__ void rankK(const unsigned long long* __restrict__ list, const uint32_t* __restrict__ cnt,
                      uint32_t* __restrict__ rank) {
  __shared__ unsigned long long lp[256];
  int b = blockIdx.z;
  int cc = (int)min(cnt[b], (uint32_t)CAP);
  if (blockIdx.x * 256 >= cc) return; // block-uniform
  int j0 = blockIdx.y * (256 * RJT);
  if (j0 >= cc) return; // block-uniform
  int i = blockIdx.x * 256 + threadIdx.x;
  unsigned long long pi = (i < cc) ? list[(size_t)b * CAP + i] : ~0ull;
  uint32_t c = 0;
#pragma unroll
  for (int tb = 0; tb < RJT; ++tb) {
    int j = j0 + tb * 256 + threadIdx.x;
    __syncthreads();
    lp[threadIdx.x] = (j < cc) ? list[(size_t)b * CAP + j] : 0ull;
    __syncthreads();
#pragma unroll 8
    for (int jj = 0; jj < 256; ++jj) c += (lp[jj] > pi) ? 1u : 0u;
  }
  if (i < cc && c) atomicAdd(&rank[(size_t)b * CAP + i], c);
}

// ---------------- K4: scatter item -> position rank; gather boxes ----------------
__global__ void scatterK(const unsigned long long* __restrict__ list,
                         const uint32_t* __restrict__ cnt, const uint32_t* __restrict__ rank,
                         const float* __restrict__ boxes, float* __restrict__ sel_score,
                         uint32_t* __restrict__ sel_idx, float* __restrict__ sel_box) {
  int b = blockIdx.y;
  int p = blockIdx.x * 256 + threadIdx.x;
  uint32_t cc = min(cnt[b], (uint32_t)CAP);
  if (p >= (int)cc) return;
  unsigned long long pk = list[(size_t)b * CAP + p];
  uint32_t r = rank[(size_t)b * CAP + p];
  if (r >= (uint32_t)KPRE) return;
  uint32_t key = (uint32_t)(pk >> 32);
  uint32_t idx = ~(uint32_t)pk;
  sel_score[b * KPRE + r] = k2f(key);
  sel_idx[b * KPRE + r] = idx;
  const float* src = boxes + ((size_t)b * N + idx) * 7;
  float* dst = sel_box + ((size_t)b * KPRE + r) * 8;
#pragma unroll
  for (int c = 0; c < 7; ++c) dst[c] = src[c];
  dst[7] = 0.f;
}

// ---------------- K5: IoU bitmask — 64x64 tiles, 1 wave/block, full occupancy ----------------
template <bool CHK>
__device__ __forceinline__ void mask_row64(int tt, const float4* __restrict__ jv,
                                           const float* __restrict__ ja, float x1i, float x2i,
                                           float y1i, float y2i, float ai, uint32_t& lo0,
                                           uint32_t& hi0, uint32_t& band) {
#pragma unroll 16
  for (int jj = 0; jj < 64; ++jj) {
    float4 v = jv[jj];
    float aj = ja[jj];
    float xx1 = fmaxf(x1i, v.x), xx2 = fminf(x2i, v.y);
    float yy1 = fmaxf(y1i, v.z), yy2 = fminf(y2i, v.w);
    float ix = fmaxf(__fsub_rn(xx2, xx1), 0.0f), iy = fmaxf(__fsub_rn(yy2, yy1), 0.0f);
    float inter = __fmul_rn(ix, iy);
    float den = fmaxf(__fsub_rn(__fadd_rn(ai, aj), inter), 1e-6f);
    float q0 = __fmul_rn(NMS_THR, den);
    float d = __fsub_rn(inter, q0);
    band |= (fabsf(d) <= __fmul_rn(q0, 1e-5f)) ? 1u : 0u;
    bool sup = d > 0.0f;
    if (CHK) sup = sup && (jj > tt);
    uint32_t bit = sup ? 1u : 0u;
    if (jj < 32) lo0 |= bit << jj; else hi0 |= bit << (jj - 32);
  }
}

__global__ __launch_bounds__(64) void maskK(const float* __restrict__ sel_box,
                                            unsigned long long* __restrict__ maskT,
                                            unsigned long long* __restrict__ Tmat) {
  int b = blockIdx.z;
  int bi = blockIdx.x; // 64-row tile
  int w = blockIdx.y;  // 64-col word
  if (w < bi) return;  // fully below diagonal: never read by nmsK (predicated)
  int t = threadIdx.x; // 0..63
  int i = bi * 64 + t;
  int j0 = w * 64;
  __shared__ float4 jv[64]; // {x1, x2, y1, y2}
  __shared__ float ja[64];
  {
    const float4* bj = (const float4*)(sel_box + ((size_t)b * KPRE + j0 + t) * 8);
    float4 lo = bj[0], hi = bj[1];
    float xj = lo.x, yj = lo.y, dxj = lo.w, dyj = hi.x;
    float hxj = __fmul_rn(dxj, 0.5f), hyj = __fmul_rn(dyj, 0.5f);
    float4 v;
    v.x = __fsub_rn(xj, hxj);
    v.y = __fadd_rn(xj, hxj);
    v.z = __fsub_rn(yj, hyj);
    v.w = __fadd_rn(yj, hyj);
    jv[t] = v;
    ja[t] = __fmul_rn(dxj, dyj);
  }
  __syncthreads();
  const float4* myb = (const float4*)(sel_box + ((size_t)b * KPRE + i) * 8);
  float4 lo = myb[0], hi = myb[1];
  float x = lo.x, y = lo.y, dx = lo.w, dy = hi.x;
  float hx = __fmul_rn(dx, 0.5f), hy = __fmul_rn(dy, 0.5f);
  float x1i = __fsub_rn(x, hx), x2i = __fadd_rn(x, hx);
  float y1i = __fsub_rn(y, hy), y2i = __fadd_rn(y, hy);
  float ai = __fmul_rn(dx, dy);
  uint32_t lo0 = 0, hi0 = 0, band = 0;
  if (w == bi)
    mask_row64<true>(t, jv, ja, x1i, x2i, y1i, y2i, ai, lo0, hi0, band);
  else
    mask_row64<false>(t, jv, ja, x1i, x2i, y1i, y2i, ai, lo0, hi0, band);
  if (__builtin_expect(__any(band != 0), 0)) { // rare: exact IEEE replay of whole tile
    lo0 = hi0 = 0;
    for (int jj = 0; jj < 64; ++jj) {
      float4 v = jv[jj];
      float aj = ja[jj];
      float xx1 = fmaxf(x1i, v.x), xx2 = fminf(x2i, v.y);
      float yy1 = fmaxf(y1i, v.z), yy2 = fminf(y2i, v.w);
      float ix = fmaxf(__fsub_rn(xx2, xx1), 0.0f), iy = fmaxf(__fsub_rn(yy2, yy1), 0.0f);
      float inter = __fmul_rn(ix, iy);
      float den = fmaxf(__fsub_rn(__fadd_rn(ai, aj), inter), 1e-6f);
      bool sup = (inter / den) > NMS_THR && (j0 + jj > i);
      uint32_t bit = sup ? 1u : 0u;
      if (jj < 32) lo0 |= bit << jj; else hi0 |= bit << (jj - 32);
    }
  }
  unsigned long long wacc = ((unsigned long long)hi0 << 32) | lo0;
  maskT[((size_t)b * MASKW + w) * KPRE + i] = wacc; // coalesced: lanes -> consecutive rows
  if (w == bi) { // fused transK: this wave IS group w's diagonal block
    unsigned long long m = wacc;
    unsigned long long T = 0ull;
#pragma unroll
    for (int j = 0; j < 64; ++j) {
      unsigned long long bj = __ballot(((m >> j) & 1ull) != 0ull);
      if (t == j) T = bj;
    }
    unsigned long long* trow = Tmat + ((size_t)b * 64 + w) * 128;
    trow[t] = T;
    trow[64 + t] = m;
  }
}

// ---------------- K6: greedy NMS — resident TD, readlane-based resolve ----------------
// Resolve chain uses v_readlane broadcasts of the per-lane diag word m (lane s holds the
// kill-word of item s) instead of ballots: all lanes redundantly maintain the uniform
// 64-bit `alive`, each killer costs ~2 readlanes (~30cy) vs 2 ballots (~120+cy).
__global__ void nmsK(const unsigned long long* __restrict__ maskT,
                     const unsigned long long* __restrict__ Tmat,
                     const float* __restrict__ sel_score,
                     uint32_t* __restrict__ kept_pos, uint32_t* __restrict__ kept_cnt) {
  __shared__ unsigned long long td[64][128]; // 64 KiB resident [T | diag]
  __shared__ uint32_t keptbuf[KPOST];
  int b = blockIdx.x;
  int t = threadIdx.x; // lane 0..63; owns remv word t

  const char* tsrc = (const char*)(Tmat + (size_t)b * 64 * 128);
  for (int g = 0; g < 64; ++g)
    async_lds16(tsrc + (size_t)g * 1024 + (size_t)t * 16, &td[g][0]);

  unsigned long long cand = 0ull; // overlaps with TD load latency
  for (int k = 0; k < 64; ++k) {
    float s = sel_score[b * KPRE + k * 64 + t];
    unsigned long long bal = __ballot(s > ROI_THR);
    if (t == k) cand = bal;
  }
  asm volatile("s_waitcnt vmcnt(0)" ::: "memory"); // TD resident (single wave, no barrier)

  const unsigned long long* mbt = maskT + (size_t)b * KPRE * MASKW + (size_t)t * KPRE;
  unsigned long long remv = 0ull;
  unsigned long long r[MAXP];
#pragma unroll
  for (int a = 0; a < MAXP; ++a) r[a] = 0ull;
  int kc = 0;

  for (int g = 0; g < 64; ++g) {
    // OR deferred alive rows from group g-1 (compiler waits loads at first use)
#pragma unroll
    for (int a = 0; a < MAXP; ++a) remv |= r[a];

    unsigned long long cw = cand & ~remv;
    unsigned long long aw =
        ((unsigned long long)(uint32_t)__builtin_amdgcn_readlane((uint32_t)(cw >> 32), g) << 32) |
        (uint32_t)__builtin_amdgcn_readlane((uint32_t)cw, g);
    if (aw) {
      unsigned long long m = td[g][64 + t]; // who I (item t) kill within group (bits > t)
      unsigned long long K = __ballot((m & aw) != 0ull); // killers among candidates
      unsigned long long alive = aw;
      unsigned long long rem = aw & K;
      while (rem) {
        int s = __ffsll((long long)rem) - 1;
        rem &= rem - 1ull;
        if ((alive >> s) & 1ull) { // s is final-alive here (ascending order)
          // broadcast lane s's kill word via readlane (uniform s)
          unsigned long long kills =
              ((unsigned long long)(uint32_t)__builtin_amdgcn_readlane((uint32_t)(m >> 32), s)
               << 32) |
              (uint32_t)__builtin_amdgcn_readlane((uint32_t)m, s);
          alive &= ~kills;
          rem &= alive;
        }
      }
      int grp = __popcll(alive);
      if ((alive >> t) & 1ull) {
        int rk = __popcll(alive & ((1ull << t) - 1ull));
        if (kc + rk < KPOST) keptbuf[kc + rk] = (uint32_t)(g * 64 + t);
      }
      kc += grp;
      // issue loads of alive rows; all-but-last batch OR'd immediately (rare, early groups)
      unsigned long long a2 = alive;
      bool again = true;
      while (again) {
#pragma unroll
        for (int a = 0; a < MAXP; ++a) {
          if (a2) {
            int s2 = __ffsll((long long)a2) - 1;
            a2 &= a2 - 1ull;
            r[a] = (t >= g) ? mbt[g * 64 + s2] : 0ull; // predicated: t<g words unwritten==0
          } else {
            r[a] = 0ull;
          }
        }
        if (a2) { // overflow batch: absorb now, go again
#pragma unroll
          for (int a = 0; a < MAXP; ++a) {
            remv |= r[a];
            r[a] = 0ull;
          }
          again = true;
        } else {
          again = false; // final batch deferred to next group's top
        }
      }
      if (kc >= KPOST) break;
    } else {
#pragma unroll
      for (int a = 0; a < MAXP; ++a) r[a] = 0ull; // nothing new in flight
    }
  }
  asm volatile("s_waitcnt vmcnt(0)" ::: "memory"); // drain in-flight row loads
  int kcc = min(kc, KPOST);
  for (int i = t; i < kcc; i += 64) kept_pos[b * KPOST + i] = keptbuf[i];
  if (t == 0) kept_cnt[b] = (uint32_t)kcc;
}

// ---------------- K7: emit outputs ----------------
__global__ void outK(const float* __restrict__ cls,
                     const float* __restrict__ sel_score, const uint32_t* __restrict__ sel_idx,
                     const float* __restrict__ sel_box,
                     const uint32_t* __restrict__ kept_pos, const uint32_t* __restrict__ kept_cnt,
                     float* __restrict__ out) {
  int b = blockIdx.y;
  int s = blockIdx.x * blockDim.x + threadIdx.x;
  if (s >= KPOST) return;
  float* oS = out;                             // (B, KPOST)
  float* oB = out + B * KPOST;                 // (B, KPOST, 7)
  float* oL = out + B * KPOST + B * KPOST * 7; // (B, KPOST)
  uint32_t kcnt = kept_cnt[b];
  if (s < (int)kcnt) {
    uint32_t pos = kept_pos[b * KPOST + s];
    oS[b * KPOST + s] = sel_score[b * KPRE + pos];
    const float* box = sel_box + ((size_t)b * KPRE + pos) * 8;
    float* dst = oB + ((size_t)b * KPOST + s) * 7;
#pragma unroll
    for (int c = 0; c < 7; ++c) dst[c] = box[c];
    uint32_t idx = sel_idx[b * KPRE + pos];
    const float* p = cls + ((size_t)b * N + idx) * C;
    float bestv = sigm(p[0]);
    int bestc = 0;
#pragma unroll
    for (int c = 1; c < C; ++c) {
      float v = sigm(p[c]);
      if (v > bestv) { bestv = v; bestc = c; }
    }
    oL[b * KPOST + s] = (float)bestc;
  } else {
    oS[b * KPOST + s] = 0.0f;
    float* dst = oB + ((size_t)b * KPOST + s) * 7;
#pragma unroll
    for (int c = 0; c < 7; ++c) dst[c] = 0.0f;
    oL[b * KPOST + s] = -1.0f;
  }
}

__global__ void sentinelK(float* out, int n) {
  int i = blockIdx.x * blockDim.x + threadIdx.x;
  if (i < n) out[i] = 1337.0f;
}

extern "C" void kernel_launch(void* const* d_in, const int* in_sizes, int n_in,
                              void* d_out, int out_size, void* d_ws, size_t ws_size,
                              hipStream_t stream) {
  const float* cls = (const float*)d_in[0];
  const float* boxes = (const float*)d_in[1];
  float* out = (float*)d_out;

  char* ws = (char*)d_ws;
  size_t off = 0;
  auto alloc = [&](size_t bytes) -> void* {
    void* p = ws + off;
    off = (off + bytes + 255) & ~(size_t)255;
    return p;
  };
  size_t mask_bytes = (size_t)B * KPRE * MASKW * 8; // 8 MB
  unsigned long long* mask = (unsigned long long*)alloc(mask_bytes); // TRANSPOSED [b][word][row]
  unsigned long long* list = (unsigned long long*)alloc((size_t)B * CAP * 8);
  uint32_t* keys = (uint32_t*)alloc((size_t)B * N * 4);
  float* sel_box = (float*)alloc((size_t)B * KPRE * 8 * 4);
  float* sel_score = (float*)alloc((size_t)B * KPRE * 4);
  uint32_t* sel_idx = (uint32_t*)alloc((size_t)B * KPRE * 4);
  uint32_t* kept_pos = (uint32_t*)alloc((size_t)B * KPOST * 4);
  uint32_t* kept_cnt = (uint32_t*)alloc(B * 4); // NOT aliased: written by nmsK after maskK
  unsigned long long* Tmat = (unsigned long long*)alloc((size_t)B * 64 * 128 * 8); // 256 KB

  // Aliases into the mask region — all dead before maskK writes mask. Only these need
  // zeroing (~147 KB); unwritten mask words are never read (nmsK loads predicated t>=g):
  uint32_t* hist0 = (uint32_t*)mask;
  uint32_t* hist1 = hist0 + B * 256;
  uint32_t* cnt = hist1 + B * 256;
  uint32_t* rank = (uint32_t*)((char*)mask + 16384);
  int zwords = (16384 + B * CAP * 4) / 4; // hists + cnt + rank

  if (off > ws_size) {
    sentinelK<<<dim3((out_size + 255) / 256), 256, 0, stream>>>(out, out_size);
    return;
  }

  zeroK<<<dim3((zwords + 255) / 256), 256, 0, stream>>>((uint32_t*)mask, zwords);
  scoreK<<<dim3(N / 256, B), 256, 0, stream>>>(cls, keys, hist0);
  histP1K<<<dim3(N / 2048, B), 256, 0, stream>>>(keys, hist0, hist1);
  compactK<<<dim3(N / 4096, B), 256, 0, stream>>>(keys, hist0, hist1, list, cnt);
  rankK<<<dim3(CAP / 256, CAP / (256 * RJT), B), 256, 0, stream>>>(list, cnt, rank);
  scatterK<<<dim3(CAP / 256, B), 256, 0, stream>>>(list, cnt, rank, boxes, sel_score, sel_idx,
                                                   sel_box);
  maskK<<<dim3(64, 64, B), 64, 0, stream>>>(sel_box, mask, Tmat);
  nmsK<<<B, 64, 0, stream>>>(mask, Tmat, sel_score, kept_pos, kept_cnt);
  outK<<<dim3((KPOST + 255) / 256, B), 256, 0, stream>>>(cls, sel_score, sel_idx, sel_box,
                                                         kept_pos, kept_cnt, out);
}

// Round 22
// 137.692 us; speedup vs baseline: 1.1226x; 1.0260x over previous
//
#include <hip/hip_runtime.h>
#include <stdint.h>

constexpr int B = 4;
constexpr int N = 262144;
constexpr int C = 10;
constexpr int KPRE = 4096;
constexpr int KPOST = 500;
constexpr float ROI_THR = 0.1f;
constexpr float NMS_THR = 0.01f;
constexpr int CAP = 8192;        // compaction capacity (>= KPRE + boundary-bin ties)
constexpr int MASKW = KPRE / 64; // 64 u64 words per mask row
constexpr int RJT = 2;           // j-tiles per rankK block
constexpr int MAXP = 32;         // deferred alive-row slots in nmsK

__device__ __forceinline__ uint32_t f2k(float f) {
  uint32_t u = __float_as_uint(f);
  return (u & 0x80000000u) ? ~u : (u | 0x80000000u);
}
__device__ __forceinline__ float k2f(uint32_t k) {
  uint32_t u = (k & 0x80000000u) ? (k ^ 0x80000000u) : ~k;
  return __uint_as_float(u);
}
__device__ __forceinline__ float sigm(float x) { return 1.0f / (1.0f + expf(-x)); }

__device__ __forceinline__ void async_lds16(const void* g, void* l) {
  __builtin_amdgcn_global_load_lds((const __attribute__((address_space(1))) void*)g,
                                   (__attribute__((address_space(3))) void*)l, 16, 0, 0);
}

// Suffix-select on a 256-bin histogram: returns (bin, residual rank). blockDim==256.
__device__ __forceinline__ uint2 select256(const uint32_t* __restrict__ h, uint32_t R,
                                           uint32_t* s, uint32_t* o2) {
  int t = threadIdx.x;
  s[t] = h[t];
  __syncthreads();
  for (int off = 1; off < 256; off <<= 1) {
    uint32_t v = s[t] + ((t + off < 256) ? s[t + off] : 0u);
    __syncthreads();
    s[t] = v;
    __syncthreads();
  }
  uint32_t suf = s[t];
  uint32_t sufn = (t < 255) ? s[t + 1] : 0u;
  if (suf >= R && R > sufn) {
    o2[0] = (uint32_t)t;
    o2[1] = R - sufn;
  }
  __syncthreads();
  uint2 r;
  r.x = o2[0];
  r.y = o2[1];
  __syncthreads(); // protect scratch reuse
  return r;
}

// ---------------- K-1: zero the aliased scratch (custom: cheap, launch-bound) ----------------
__global__ void zeroK(uint32_t* __restrict__ p, int n) {
  int i = blockIdx.x * 256 + threadIdx.x;
  if (i < n) p[i] = 0u;
}

// ---------------- K0: keys + pass-0 histogram (sigmoid commutes with max) ----------------
__global__ void scoreK(const float* __restrict__ cls, uint32_t* __restrict__ keys,
                       uint32_t* __restrict__ hist0) {
  __shared__ float ls[2560]; // 256 items x 10 classes
  __shared__ uint32_t h[256];
  int b = blockIdx.y;
  int t = threadIdx.x;
  h[t] = 0;
  size_t base = ((size_t)b * N + (size_t)blockIdx.x * 256) * C;
  const float2* g2 = (const float2*)(cls + base);
  float2* l2 = (float2*)ls;
#pragma unroll
  for (int r = 0; r < 5; ++r) l2[r * 256 + t] = g2[r * 256 + t]; // coalesced 512B/wave
  __syncthreads();
  const float* mine = ls + t * 10;
  float m = mine[0];
#pragma unroll
  for (int c = 1; c < C; ++c) m = fmaxf(m, mine[c]); // max logit
  float p = sigm(m);                                  // == max prob (monotone)
  float sc = (p > ROI_THR) ? p : -1.0f;
  uint32_t k = f2k(sc);
  keys[(size_t)b * N + blockIdx.x * 256 + t] = k;
  atomicAdd(&h[k >> 24], 1u);
  __syncthreads();
  if (h[t]) atomicAdd(&hist0[b * 256 + t], h[t]);
}

// ---------------- K1: byte-1 histogram among items matching pass-0 byte ----------------
__global__ void histP1K(const uint32_t* __restrict__ keys, const uint32_t* __restrict__ hist0,
                        uint32_t* __restrict__ hist1) {
  __shared__ uint32_t s[256];
  __shared__ uint32_t o2[2];
  __shared__ uint32_t h[256];
  int b = blockIdx.y;
  int t = threadIdx.x;
  uint2 s0 = select256(hist0 + b * 256, (uint32_t)KPRE, s, o2);
  h[t] = 0;
  __syncthreads();
  uint32_t pref = s0.x;
  const uint4* kb4 = (const uint4*)(keys + (size_t)b * N);
#pragma unroll
  for (int r = 0; r < 2; ++r) {
    uint4 kv = kb4[blockIdx.x * 512 + r * 256 + t];
#pragma unroll
    for (int j = 0; j < 4; ++j) {
      uint32_t k = (&kv.x)[j];
      if ((k >> 24) == pref) atomicAdd(&h[(k >> 16) & 255u], 1u);
    }
  }
  __syncthreads();
  if (h[t]) atomicAdd(&hist1[b * 256 + t], h[t]);
}

// ---------------- K2: 16-bit threshold; block-aggregated stream compaction ----------------
__global__ void compactK(const uint32_t* __restrict__ keys, const uint32_t* __restrict__ hist0,
                         const uint32_t* __restrict__ hist1, unsigned long long* __restrict__ list,
                         uint32_t* __restrict__ cnt) {
  __shared__ uint32_t s[256];
  __shared__ uint32_t o2[2];
  __shared__ uint32_t scan[256];
  __shared__ uint32_t baseSh;
  int b = blockIdx.y;
  int t = threadIdx.x;
  uint2 s0 = select256(hist0 + b * 256, (uint32_t)KPRE, s, o2);
  uint2 s1 = select256(hist1 + b * 256, s0.y, s, o2);
  uint32_t T = ((s0.x << 8) | s1.x) << 16;
  const uint4* kb4 = (const uint4*)(keys + (size_t)b * N);
  uint4 kv[4];
#pragma unroll
  for (int r = 0; r < 4; ++r) kv[r] = kb4[blockIdx.x * 1024 + r * 256 + t];
  uint32_t c = 0;
#pragma unroll
  for (int r = 0; r < 4; ++r)
#pragma unroll
    for (int j = 0; j < 4; ++j) c += ((&kv[r].x)[j] >= T) ? 1u : 0u;
  scan[t] = c;
  __syncthreads();
  for (int off = 1; off < 256; off <<= 1) {
    uint32_t v = scan[t] + ((t >= off) ? scan[t - off] : 0u);
    __syncthreads();
    scan[t] = v;
    __syncthreads();
  }
  uint32_t excl = scan[t] - c;
  if (t == 255) baseSh = atomicAdd(&cnt[b], scan[255]);
  __syncthreads();
  uint32_t pos = baseSh + excl;
#pragma unroll
  for (int r = 0; r < 4; ++r)
#pragma unroll
    for (int j = 0; j < 4; ++j) {
      uint32_t k = (&kv[r].x)[j];
      if (k >= T) {
        uint32_t n = (blockIdx.x * 1024 + r * 256 + t) * 4 + j;
        if (pos < CAP)
          list[(size_t)b * CAP + pos] = ((unsigned long long)k << 32) | (uint32_t)(~n);
        pos++;
      }
    }
}

// ---------------- K3: exact rank by counting, j-split for occupancy ----------------
__global__ void rankK(const unsigned long long* __restrict__ list, const uint32_t* __restrict__ cnt,
                      uint32_t* __restrict__ rank) {
  __shared__ unsigned long long lp[256];
  int b = blockIdx.z;
  int cc = (int)min(cnt[b], (uint32_t)CAP);
  if (blockIdx.x * 256 >= cc) return; // block-uniform
  int j0 = blockIdx.y * (256 * RJT);
  if (j0 >= cc) return; // block-uniform
  int i = blockIdx.x * 256 + threadIdx.x;
  unsigned long long pi = (i < cc) ? list[(size_t)b * CAP + i] : ~0ull;
  uint32_t c = 0;
#pragma unroll
  for (int tb = 0; tb < RJT; ++tb) {
    int j = j0 + tb * 256 + threadIdx.x;
    __syncthreads();
    lp[threadIdx.x] = (j < cc) ? list[(size_t)b * CAP + j] : 0ull;
    __syncthreads();
#pragma unroll 8
    for (int jj = 0; jj < 256; ++jj) c += (lp[jj] > pi) ? 1u : 0u;
  }
  if (i < cc && c) atomicAdd(&rank[(size_t)b * CAP + i], c);
}

// ---------------- K4: scatter item -> position rank; gather boxes ----------------
__global__ void scatterK(const unsigned long long* __restrict__ list,
                         const uint32_t* __restrict__ cnt, const uint32_t* __restrict__ rank,
                         const float* __restrict__ boxes, float* __restrict__ sel_score,
                         uint32_t* __restrict__ sel_idx, float* __restrict__ sel_box) {
  int b = blockIdx.y;
  int p = blockIdx.x * 256 + threadIdx.x;
  uint32_t cc = min(cnt[b], (uint32_t)CAP);
  if (p >= (int)cc) return;
  unsigned long long pk = list[(size_t)b * CAP + p];
  uint32_t r = rank[(size_t)b * CAP + p];
  if (r >= (uint32_t)KPRE) return;
  uint32_t key = (uint32_t)(pk >> 32);
  uint32_t idx = ~(uint32_t)pk;
  sel_score[b * KPRE + r] = k2f(key);
  sel_idx[b * KPRE + r] = idx;
  const float* src = boxes + ((size_t)b * N + idx) * 7;
  float* dst = sel_box + ((size_t)b * KPRE + r) * 8;
#pragma unroll
  for (int c = 0; c < 7; ++c) dst[c] = src[c];
  dst[7] = 0.f;
}

// ---------------- K5: IoU bitmask — 64x64 tiles, 1 wave/block, full occupancy ----------------
template <bool CHK>
__device__ __forceinline__ void mask_row64(int tt, const float4* __restrict__ jv,
                                           const float* __restrict__ ja, float x1i, float x2i,
                                           float y1i, float y2i, float ai, uint32_t& lo0,
                                           uint32_t& hi0, uint32_t& band) {
#pragma unroll 16
  for (int jj = 0; jj < 64; ++jj) {
    float4 v = jv[jj];
    float aj = ja[jj];
    float xx1 = fmaxf(x1i, v.x), xx2 = fminf(x2i, v.y);
    float yy1 = fmaxf(y1i, v.z), yy2 = fminf(y2i, v.w);
    float ix = fmaxf(__fsub_rn(xx2, xx1), 0.0f), iy = fmaxf(__fsub_rn(yy2, yy1), 0.0f);
    float inter = __fmul_rn(ix, iy);
    float den = fmaxf(__fsub_rn(__fadd_rn(ai, aj), inter), 1e-6f);
    float q0 = __fmul_rn(NMS_THR, den);
    float d = __fsub_rn(inter, q0);
    band |= (fabsf(d) <= __fmul_rn(q0, 1e-5f)) ? 1u : 0u;
    bool sup = d > 0.0f;
    if (CHK) sup = sup && (jj > tt);
    uint32_t bit = sup ? 1u : 0u;
    if (jj < 32) lo0 |= bit << jj; else hi0 |= bit << (jj - 32);
  }
}

__global__ __launch_bounds__(64) void maskK(const float* __restrict__ sel_box,
                                            unsigned long long* __restrict__ maskT,
                                            unsigned long long* __restrict__ Tmat) {
  int b = blockIdx.z;
  int bi = blockIdx.x; // 64-row tile
  int w = blockIdx.y;  // 64-col word
  if (w < bi) return;  // fully below diagonal: never read by nmsK (predicated)
  int t = threadIdx.x; // 0..63
  int i = bi * 64 + t;
  int j0 = w * 64;
  __shared__ float4 jv[64]; // {x1, x2, y1, y2}
  __shared__ float ja[64];
  {
    const float4* bj = (const float4*)(sel_box + ((size_t)b * KPRE + j0 + t) * 8);
    float4 lo = bj[0], hi = bj[1];
    float xj = lo.x, yj = lo.y, dxj = lo.w, dyj = hi.x;
    float hxj = __fmul_rn(dxj, 0.5f), hyj = __fmul_rn(dyj, 0.5f);
    float4 v;
    v.x = __fsub_rn(xj, hxj);
    v.y = __fadd_rn(xj, hxj);
    v.z = __fsub_rn(yj, hyj);
    v.w = __fadd_rn(yj, hyj);
    jv[t] = v;
    ja[t] = __fmul_rn(dxj, dyj);
  }
  __syncthreads();
  const float4* myb = (const float4*)(sel_box + ((size_t)b * KPRE + i) * 8);
  float4 lo = myb[0], hi = myb[1];
  float x = lo.x, y = lo.y, dx = lo.w, dy = hi.x;
  float hx = __fmul_rn(dx, 0.5f), hy = __fmul_rn(dy, 0.5f);
  float x1i = __fsub_rn(x, hx), x2i = __fadd_rn(x, hx);
  float y1i = __fsub_rn(y, hy), y2i = __fadd_rn(y, hy);
  float ai = __fmul_rn(dx, dy);
  uint32_t lo0 = 0, hi0 = 0, band = 0;
  if (w == bi)
    mask_row64<true>(t, jv, ja, x1i, x2i, y1i, y2i, ai, lo0, hi0, band);
  else
    mask_row64<false>(t, jv, ja, x1i, x2i, y1i, y2i, ai, lo0, hi0, band);
  if (__builtin_expect(__any(band != 0), 0)) { // rare: exact IEEE replay of whole tile
    lo0 = hi0 = 0;
    for (int jj = 0; jj < 64; ++jj) {
      float4 v = jv[jj];
      float aj = ja[jj];
      float xx1 = fmaxf(x1i, v.x), xx2 = fminf(x2i, v.y);
      float yy1 = fmaxf(y1i, v.z), yy2 = fminf(y2i, v.w);
      float ix = fmaxf(__fsub_rn(xx2, xx1), 0.0f), iy = fmaxf(__fsub_rn(yy2, yy1), 0.0f);
      float inter = __fmul_rn(ix, iy);
      float den = fmaxf(__fsub_rn(__fadd_rn(ai, aj), inter), 1e-6f);
      bool sup = (inter / den) > NMS_THR && (j0 + jj > i);
      uint32_t bit = sup ? 1u : 0u;
      if (jj < 32) lo0 |= bit << jj; else hi0 |= bit << (jj - 32);
    }
  }
  unsigned long long wacc = ((unsigned long long)hi0 << 32) | lo0;
  maskT[((size_t)b * MASKW + w) * KPRE + i] = wacc; // coalesced: lanes -> consecutive rows
  if (w == bi) { // diag row for nmsK (T-transpose removed: readlane resolve doesn't need it)
    Tmat[((size_t)b * 64 + w) * 128 + t] = wacc;
  }
}

// ---------------- K6: greedy NMS — resident diag, readlane resolve, hoisted LDS read ----------------
// m-read hoisted above the deferred-OR block so its LDS latency overlaps the vmcnt wait.
// Diag table is 32KB (only the kill-words; T half unused since readlane resolve).
__global__ void nmsK(const unsigned long long* __restrict__ maskT,
                     const unsigned long long* __restrict__ Tmat,
                     const float* __restrict__ sel_score,
                     uint32_t* __restrict__ kept_pos, uint32_t* __restrict__ kept_cnt) {
  __shared__ unsigned long long td[64][64]; // 32 KiB resident diag
  __shared__ uint32_t keptbuf[KPOST];
  int b = blockIdx.x;
  int t = threadIdx.x; // lane 0..63; owns remv word t

  const char* tsrc = (const char*)(Tmat + (size_t)b * 64 * 128);
  if (t < 32) { // 512B per group: lanes 0..31 write td[g][0..63] (wave-uniform base + lane*16)
    for (int g = 0; g < 64; ++g)
      async_lds16(tsrc + (size_t)g * 1024 + (size_t)t * 16, &td[g][0]);
  }

  unsigned long long cand = 0ull; // overlaps with diag load latency
  for (int k = 0; k < 64; ++k) {
    float s = sel_score[b * KPRE + k * 64 + t];
    unsigned long long bal = __ballot(s > ROI_THR);
    if (t == k) cand = bal;
  }
  asm volatile("s_waitcnt vmcnt(0)" ::: "memory"); // diag resident (single wave, no barrier)

  const unsigned long long* mbt = maskT + (size_t)b * KPRE * MASKW + (size_t)t * KPRE;
  unsigned long long remv = 0ull;
  unsigned long long r[MAXP];
#pragma unroll
  for (int a = 0; a < MAXP; ++a) r[a] = 0ull;
  int kc = 0;

  for (int g = 0; g < 64; ++g) {
    unsigned long long m = td[g][t]; // hoisted: LDS latency overlaps the vmcnt wait below
    // OR deferred alive rows from group g-1 (compiler waits loads at first use)
#pragma unroll
    for (int a = 0; a < MAXP; ++a) remv |= r[a];

    unsigned long long cw = cand & ~remv;
    unsigned long long aw =
        ((unsigned long long)(uint32_t)__builtin_amdgcn_readlane((uint32_t)(cw >> 32), g) << 32) |
        (uint32_t)__builtin_amdgcn_readlane((uint32_t)cw, g);
    if (aw) {
      unsigned long long K = __ballot((m & aw) != 0ull); // killers among candidates
      unsigned long long alive = aw;
      unsigned long long rem = aw & K;
      while (rem) {
        int s = __ffsll((long long)rem) - 1;
        rem &= rem - 1ull;
        if ((alive >> s) & 1ull) { // s is final-alive here (ascending order)
          unsigned long long kills =
              ((unsigned long long)(uint32_t)__builtin_amdgcn_readlane((uint32_t)(m >> 32), s)
               << 32) |
              (uint32_t)__builtin_amdgcn_readlane((uint32_t)m, s);
          alive &= ~kills;
          rem &= alive;
        }
      }
      int grp = __popcll(alive);
      if ((alive >> t) & 1ull) {
        int rk = __popcll(alive & ((1ull << t) - 1ull));
        if (kc + rk < KPOST) keptbuf[kc + rk] = (uint32_t)(g * 64 + t);
      }
      kc += grp;
      // issue loads of alive rows; all-but-last batch OR'd immediately (rare, early groups)
      unsigned long long a2 = alive;
      bool again = true;
      while (again) {
#pragma unroll
        for (int a = 0; a < MAXP; ++a) {
          if (a2) {
            int s2 = __ffsll((long long)a2) - 1;
            a2 &= a2 - 1ull;
            r[a] = (t >= g) ? mbt[g * 64 + s2] : 0ull; // predicated: t<g words unwritten==0
          } else {
            r[a] = 0ull;
          }
        }
        if (a2) { // overflow batch: absorb now, go again
#pragma unroll
          for (int a = 0; a < MAXP; ++a) {
            remv |= r[a];
            r[a] = 0ull;
          }
          again = true;
        } else {
          again = false; // final batch deferred to next group's top
        }
      }
      if (kc >= KPOST) break;
    } else {
#pragma unroll
      for (int a = 0; a < MAXP; ++a) r[a] = 0ull; // nothing new in flight
    }
  }
  asm volatile("s_waitcnt vmcnt(0)" ::: "memory"); // drain in-flight row loads
  int kcc = min(kc, KPOST);
  for (int i = t; i < kcc; i += 64) kept_pos[b * KPOST + i] = keptbuf[i];
  if (t == 0) kept_cnt[b] = (uint32_t)kcc;
}

// ---------------- K7: emit outputs ----------------
__global__ void outK(const float* __restrict__ cls,
                     const float* __restrict__ sel_score, const uint32_t* __restrict__ sel_idx,
                     const float* __restrict__ sel_box,
                     const uint32_t* __restrict__ kept_pos, const uint32_t* __restrict__ kept_cnt,
                     float* __restrict__ out) {
  int b = blockIdx.y;
  int s = blockIdx.x * blockDim.x + threadIdx.x;
  if (s >= KPOST) return;
  float* oS = out;                             // (B, KPOST)
  float* oB = out + B * KPOST;                 // (B, KPOST, 7)
  float* oL = out + B * KPOST + B * KPOST * 7; // (B, KPOST)
  uint32_t kcnt = kept_cnt[b];
  if (s < (int)kcnt) {
    uint32_t pos = kept_pos[b * KPOST + s];
    oS[b * KPOST + s] = sel_score[b * KPRE + pos];
    const float* box = sel_box + ((size_t)b * KPRE + pos) * 8;
    float* dst = oB + ((size_t)b * KPOST + s) * 7;
#pragma unroll
    for (int c = 0; c < 7; ++c) dst[c] = box[c];
    uint32_t idx = sel_idx[b * KPRE + pos];
    const float* p = cls + ((size_t)b * N + idx) * C;
    float bestv = sigm(p[0]);
    int bestc = 0;
#pragma unroll
    for (int c = 1; c < C; ++c) {
      float v = sigm(p[c]);
      if (v > bestv) { bestv = v; bestc = c; }
    }
    oL[b * KPOST + s] = (float)bestc;
  } else {
    oS[b * KPOST + s] = 0.0f;
    float* dst = oB + ((size_t)b * KPOST + s) * 7;
#pragma unroll
    for (int c = 0; c < 7; ++c) dst[c] = 0.0f;
    oL[b * KPOST + s] = -1.0f;
  }
}

__global__ void sentinelK(float* out, int n) {
  int i = blockIdx.x * blockDim.x + threadIdx.x;
  if (i < n) out[i] = 1337.0f;
}

extern "C" void kernel_launch(void* const* d_in, const int* in_sizes, int n_in,
                              void* d_out, int out_size, void* d_ws, size_t ws_size,
                              hipStream_t stream) {
  const float* cls = (const float*)d_in[0];
  const float* boxes = (const float*)d_in[1];
  float* out = (float*)d_out;

  char* ws = (char*)d_ws;
  size_t off = 0;
  auto alloc = [&](size_t bytes) -> void* {
    void* p = ws + off;
    off = (off + bytes + 255) & ~(size_t)255;
    return p;
  };
  size_t mask_bytes = (size_t)B * KPRE * MASKW * 8; // 8 MB
  unsigned long long* mask = (unsigned long long*)alloc(mask_bytes); // TRANSPOSED [b][word][row]
  unsigned long long* list = (unsigned long long*)alloc((size_t)B * CAP * 8);
  uint32_t* keys = (uint32_t*)alloc((size_t)B * N * 4);
  float* sel_box = (float*)alloc((size_t)B * KPRE * 8 * 4);
  float* sel_score = (float*)alloc((size_t)B * KPRE * 4);
  uint32_t* sel_idx = (uint32_t*)alloc((size_t)B * KPRE * 4);
  uint32_t* kept_pos = (uint32_t*)alloc((size_t)B * KPOST * 4);
  uint32_t* kept_cnt = (uint32_t*)alloc(B * 4); // NOT aliased: written by nmsK after maskK
  unsigned long long* Tmat = (unsigned long long*)alloc((size_t)B * 64 * 128 * 8); // 256 KB

  // Aliases into the mask region — all dead before maskK writes mask. Only these need
  // zeroing (~147 KB); unwritten mask words are never read (nmsK loads predicated t>=g):
  uint32_t* hist0 = (uint32_t*)mask;
  uint32_t* hist1 = hist0 + B * 256;
  uint32_t* cnt = hist1 + B * 256;
  uint32_t* rank = (uint32_t*)((char*)mask + 16384);
  int zwords = (16384 + B * CAP * 4) / 4; // hists + cnt + rank

  if (off > ws_size) {
    sentinelK<<<dim3((out_size + 255) / 256), 256, 0, stream>>>(out, out_size);
    return;
  }

  zeroK<<<dim3((zwords + 255) / 256), 256, 0, stream>>>((uint32_t*)mask, zwords);
  scoreK<<<dim3(N / 256, B), 256, 0, stream>>>(cls, keys, hist0);
  histP1K<<<dim3(N / 2048, B), 256, 0, stream>>>(keys, hist0, hist1);
  compactK<<<dim3(N / 4096, B), 256, 0, stream>>>(keys, hist0, hist1, list, cnt);
  rankK<<<dim3(CAP / 256, CAP / (256 * RJT), B), 256, 0, stream>>>(list, cnt, rank);
  scatterK<<<dim3(CAP / 256, B), 256, 0, stream>>>(list, cnt, rank, boxes, sel_score, sel_idx,
                                                   sel_box);
  maskK<<<dim3(64, 64, B), 64, 0, stream>>>(sel_box, mask, Tmat);
  nmsK<<<B, 64, 0, stream>>>(mask, Tmat, sel_score, kept_pos, kept_cnt);
  outK<<<dim3((KPOST + 255) / 256, B), 256, 0, stream>>>(cls, sel_score, sel_idx, sel_box,
                                                         kept_pos, kept_cnt, out);
}